// Round 8
// baseline (429.851 us; speedup 1.0000x reference)
//
#include <hip/hip_runtime.h>

#define HD 16
#define DHEAD 64
#define DMODEL 1024
#define BB 2
#define SS 2048
#define MTOT (BB*SS)   // 4096
#define LOG2E 1.44269504f

typedef float f32x4 __attribute__((ext_vector_type(4)));
typedef float f32x16 __attribute__((ext_vector_type(16)));
typedef __bf16 bf16x8 __attribute__((ext_vector_type(8)));
typedef unsigned short u16x8 __attribute__((ext_vector_type(8)));
typedef unsigned int u32x2 __attribute__((ext_vector_type(2)));
typedef unsigned int u32x4 __attribute__((ext_vector_type(4)));

__device__ __forceinline__ unsigned short f2bf(float f) {
    unsigned int u = __builtin_bit_cast(unsigned int, f);
    unsigned int r = (u + 0x7fffu + ((u >> 16) & 1u)) >> 16;   // RNE
    return (unsigned short)r;
}

__device__ __forceinline__ bf16x8 ld8(const unsigned short* p) {
    u16x8 v = *reinterpret_cast<const u16x8*>(p);
    return __builtin_bit_cast(bf16x8, v);
}

__device__ __forceinline__ void gload_lds16(const unsigned short* g, unsigned short* l) {
    __builtin_amdgcn_global_load_lds(
        (const __attribute__((address_space(1))) void*)g,
        (__attribute__((address_space(3))) void*)l, 16, 0, 0);
}

__device__ __forceinline__ void gload_lds16b(const char* g, char* l) {
    __builtin_amdgcn_global_load_lds(
        (const __attribute__((address_space(1))) void*)g,
        (__attribute__((address_space(3))) void*)l, 16, 0, 0);
}

__device__ __forceinline__ unsigned cvt_pk_bf16(float lo, float hi) {
    unsigned r;
    asm("v_cvt_pk_bf16_f32 %0, %1, %2" : "=v"(r) : "v"(lo), "v"(hi));
    return r;
}

// ---------------- fp32 -> bf16 converts ----------------
__global__ __launch_bounds__(256) void cvt_kernel(const float* __restrict__ in,
                                                  unsigned short* __restrict__ out, int n4) {
    int i = blockIdx.x * blockDim.x + threadIdx.x;
    if (i < n4) {
        float4 v = reinterpret_cast<const float4*>(in)[i];
        ushort4 o;
        o.x = f2bf(v.x); o.y = f2bf(v.y); o.z = f2bf(v.z); o.w = f2bf(v.w);
        reinterpret_cast<ushort4*>(out)[i] = o;
    }
}

__global__ __launch_bounds__(256) void cvtw_kernel(const float* __restrict__ w0, const float* __restrict__ w1,
                                                   const float* __restrict__ w2, const float* __restrict__ w3,
                                                   unsigned short* __restrict__ o0, unsigned short* __restrict__ o1,
                                                   unsigned short* __restrict__ o2, unsigned short* __restrict__ o3) {
    int z = blockIdx.y;
    const float* in = (z == 0) ? w0 : (z == 1) ? w1 : (z == 2) ? w2 : w3;
    unsigned short* out = (z == 0) ? o0 : (z == 1) ? o1 : (z == 2) ? o2 : o3;
    int i = blockIdx.x * blockDim.x + threadIdx.x;
    float4 v = reinterpret_cast<const float4*>(in)[i];
    ushort4 o;
    o.x = f2bf(v.x); o.y = f2bf(v.y); o.z = f2bf(v.z); o.w = f2bf(v.w);
    reinterpret_cast<ushort4*>(out)[i] = o;
}

// ---------------- GEMM core: C[128x128] = A[M,K] * B[N,K]^T (single-buf, syncthreads) ----------------
__device__ __forceinline__ void gemm_core(const unsigned short* __restrict__ A,
                                          const unsigned short* __restrict__ Bm,
                                          unsigned short* Als, unsigned short* Bls,
                                          int m0, int n0, int K, f32x4 acc[4][4]) {
    int t    = threadIdx.x;
    int wv   = t >> 6, lane = t & 63;
    int lrow = lane & 15, lgrp = lane >> 4;
    int wr   = wv >> 1, wc = wv & 1;
    int srow = t & 127, skb = t >> 7;

    const unsigned short* Ag = A  + (size_t)(m0 + srow) * K + skb * 8;
    const unsigned short* Bg = Bm + (size_t)(n0 + srow) * K + skb * 8;

    for (int k0 = 0; k0 < K; k0 += 32) {
#pragma unroll
        for (int i = 0; i < 2; ++i) {
            gload_lds16(Ag + k0 + i * 16, Als + i * 2048 + wv * 512);
            gload_lds16(Bg + k0 + i * 16, Bls + i * 2048 + wv * 512);
        }
        __syncthreads();

        bf16x8 af[4], bfr[4];
#pragma unroll
        for (int i = 0; i < 4; ++i) {
            af[i]  = ld8(&Als[lgrp * 1024 + (wr * 64 + i * 16 + lrow) * 8]);
            bfr[i] = ld8(&Bls[lgrp * 1024 + (wc * 64 + i * 16 + lrow) * 8]);
        }
#pragma unroll
        for (int mi = 0; mi < 4; ++mi)
#pragma unroll
            for (int ni = 0; ni < 4; ++ni)
                acc[mi][ni] = __builtin_amdgcn_mfma_f32_16x16x32_bf16(af[mi], bfr[ni], acc[mi][ni], 0, 0, 0);
        __syncthreads();
    }
}

// ---------------- QKV projection (grid.z selects Q/K/V) ----------------
__global__ __launch_bounds__(256) void gemm_qkv(
    const unsigned short* __restrict__ xb,
    const unsigned short* __restrict__ Wqb, const unsigned short* __restrict__ Wkb,
    const unsigned short* __restrict__ Wvb,
    const float* __restrict__ bq, const float* __restrict__ bk, const float* __restrict__ bv,
    unsigned short* __restrict__ Qo, unsigned short* __restrict__ Ko, unsigned short* __restrict__ VTo) {
    __shared__ unsigned short Als[4096], Bls[4096];
    int z = blockIdx.z;
    const unsigned short* Bm = (z == 0) ? Wqb : (z == 1) ? Wkb : Wvb;
    const float* bias = (z == 0) ? bq : (z == 1) ? bk : bv;
    int m0 = blockIdx.y * 128, n0 = blockIdx.x * 128;

    f32x4 acc[4][4];
#pragma unroll
    for (int mi = 0; mi < 4; ++mi)
#pragma unroll
        for (int ni = 0; ni < 4; ++ni) acc[mi][ni] = (f32x4){0.f, 0.f, 0.f, 0.f};

    gemm_core(xb, Bm, Als, Bls, m0, n0, DMODEL, acc);

    int t = threadIdx.x, wv = t >> 6, lane = t & 63;
    int lrow = lane & 15, lgrp = lane >> 4;
    int wr = wv >> 1, wc = wv & 1;
    float scale = (z == 0) ? 0.125f : 1.0f;   // fold 1/sqrt(64) into Q

#pragma unroll
    for (int mi = 0; mi < 4; ++mi) {
#pragma unroll
        for (int ni = 0; ni < 4; ++ni) {
            int col = n0 + wc * 64 + ni * 16 + lrow;
            int h = col >> 6, dh = col & 63;
            float bi = bias[col];
            if (z == 2) {
                int row0 = m0 + wr * 64 + mi * 16 + lgrp * 4;
                int b = row0 >> 11, s0 = row0 & 2047;
                ushort4 pk;
                pk.x = f2bf(acc[mi][ni][0] + bi);
                pk.y = f2bf(acc[mi][ni][1] + bi);
                pk.z = f2bf(acc[mi][ni][2] + bi);
                pk.w = f2bf(acc[mi][ni][3] + bi);
                *reinterpret_cast<ushort4*>(&VTo[((size_t)((b * HD + h) * DHEAD + dh)) * SS + s0]) = pk;
            } else {
#pragma unroll
                for (int r = 0; r < 4; ++r) {
                    int row = m0 + wr * 64 + mi * 16 + lgrp * 4 + r;
                    int b = row >> 11, s = row & 2047;
                    unsigned short v16 = f2bf((acc[mi][ni][r] + bi) * scale);
                    unsigned short* o = (z == 0) ? Qo : Ko;                           // [bh][s][dh]
                    o[((size_t)((b * HD + h) * SS + s)) * DHEAD + dh] = v16;
                }
            }
        }
    }
}

// ---------------- flash attention (ablation template) ----------------
// V=0 full (real output). V=1 NOSTAGE (no gload_lds/barriers/waits; ds_reads on
// poison, addr obfuscated vs LICM). V=2 NOSM (P = bitcast scores). V=4 floor.
template<int V>
__global__ __launch_bounds__(256) void attn_abl(
    const unsigned short* __restrict__ Qb, const unsigned short* __restrict__ Kb,
    const unsigned short* __restrict__ VTb, unsigned short* __restrict__ ctxo) {
    constexpr bool STAGE = (V != 1 && V != 4);
    constexpr bool SM    = (V != 2 && V != 4);
    __shared__ unsigned short Kls[2][4096];   // [64 t][64 dh] bf16, swizzled
    __shared__ unsigned short Vls[2][4096];   // [64 d][64 t]  bf16, swizzled
    int bh = blockIdx.y;
    int q0 = blockIdx.x * 128;
    int t = threadIdx.x, wv = t >> 6, lane = t & 63;
    int q5 = lane & 31, hi = lane >> 5;
    const unsigned short* Qh  = Qb  + (size_t)bh * SS * DHEAD;
    const char* Khc  = (const char*)(Kb  + (size_t)bh * SS * DHEAD);
    const char* VThc = (const char*)(VTb + (size_t)bh * DHEAD * SS);
    int qr = q0 + wv * 32;

    bf16x8 qf[4];
#pragma unroll
    for (int m = 0; m < 4; ++m)
        qf[m] = ld8(&Qh[(size_t)(qr + q5) * DHEAD + m * 16 + hi * 8]);

    int c0 = t, c1 = t + 256;
    int kr0 = c0 >> 3, cb0 = ((c0 & 7) << 4) ^ ((kr0 & 7) << 4);
    int kr1 = c1 >> 3, cb1 = ((c1 & 7) << 4) ^ ((kr1 & 7) << 4);

    f32x16 oo[2];
    oo[0] = (f32x16)0.f; oo[1] = (f32x16)0.f;
    float lp = 0.f;
    float mrun = 0.f;

    auto stage = [&](int buf, int t0) {
        gload_lds16b(Khc + (size_t)(t0 + kr0) * 128 + cb0, (char*)&Kls[buf][0] + c0 * 16);
        gload_lds16b(Khc + (size_t)(t0 + kr1) * 128 + cb1, (char*)&Kls[buf][0] + c1 * 16);
        gload_lds16b(VThc + ((size_t)kr0 * SS + t0) * 2 + cb0, (char*)&Vls[buf][0] + c0 * 16);
        gload_lds16b(VThc + ((size_t)kr1 * SS + t0) * 2 + cb1, (char*)&Vls[buf][0] + c1 * 16);
    };

    if constexpr (STAGE) stage(0, 0);
    int buf = 0;

    for (int t0 = 0; t0 < SS; t0 += 64) {
        const char *kls, *vls;
        if constexpr (STAGE) {
            __builtin_amdgcn_s_barrier();
            if (t0 + 64 < SS) {
                stage(buf ^ 1, t0 + 64);
                asm volatile("s_waitcnt vmcnt(4)" ::: "memory");
            } else {
                asm volatile("s_waitcnt vmcnt(0)" ::: "memory");
            }
            __builtin_amdgcn_sched_barrier(0);
            __builtin_amdgcn_s_barrier();
            __builtin_amdgcn_sched_barrier(0);
            kls = (const char*)&Kls[buf][0];
            vls = (const char*)&Vls[buf][0];
        } else {
            // opaque buf-like toggle so ds_reads can't be hoisted out of the loop
            int obf;
            asm volatile("v_mov_b32 %0, %1" : "=v"(obf) : "v"(t0));
            kls = (const char*)&Kls[0][0] + ((obf & 64) << 7);
            vls = (const char*)&Vls[0][0] + ((obf & 64) << 7);
        }

        f32x16 sc[2];
        __builtin_amdgcn_s_setprio(1);
#pragma unroll
        for (int tb = 0; tb < 2; ++tb) {
            int row = tb * 32 + q5;
            int rsw = (row & 7) << 4;
            f32x16 s = (f32x16)0.f;
#pragma unroll
            for (int m = 0; m < 4; ++m) {
                bf16x8 kf = *reinterpret_cast<const bf16x8*>(kls + row * 128 + ((m * 32 + hi * 16) ^ rsw));
                s = __builtin_amdgcn_mfma_f32_32x32x16_bf16(kf, qf[m], s, 0, 0, 0);
            }
            sc[tb] = s;
        }
        __builtin_amdgcn_s_setprio(0);

        u32x4 paw[4];
        if constexpr (SM) {
            float lm = sc[0][0];
#pragma unroll
            for (int r = 1; r < 16; ++r) lm = fmaxf(lm, sc[0][r]);
#pragma unroll
            for (int r = 0; r < 16; ++r) lm = fmaxf(lm, sc[1][r]);
            u32x2 sw = __builtin_amdgcn_permlane32_swap(__builtin_bit_cast(unsigned, lm),
                                                        __builtin_bit_cast(unsigned, lm), false, false);
            float rowmax = fmaxf(__builtin_bit_cast(float, sw[0]), __builtin_bit_cast(float, sw[1]));

            if (__any(rowmax > mrun + 8.f)) {
                float mn = fmaxf(mrun, rowmax);
                float al = exp2f((mrun - mn) * LOG2E);
                mrun = mn;
                lp *= al;
#pragma unroll
                for (int r = 0; r < 16; ++r) {
                    float alr = __shfl(al, (r & 3) + 8 * (r >> 2) + 4 * hi);
                    oo[0][r] *= alr; oo[1][r] *= alr;
                }
            }

            float ml = mrun * LOG2E;
            float ps = 0.f;
#pragma unroll
            for (int tb = 0; tb < 2; ++tb)
#pragma unroll
                for (int r = 0; r < 16; ++r) {
                    float p = exp2f(__builtin_fmaf(sc[tb][r], LOG2E, -ml));
                    sc[tb][r] = p;
                    ps += p;
                }
            lp += ps;

#pragma unroll
            for (int tb = 0; tb < 2; ++tb) {
#pragma unroll
                for (int u2 = 0; u2 < 2; ++u2) {
#pragma unroll
                    for (int e = 0; e < 2; ++e) {
                        unsigned wd = cvt_pk_bf16(sc[tb][8 * u2 + 2 * e], sc[tb][8 * u2 + 2 * e + 1]);
                        unsigned ws = cvt_pk_bf16(sc[tb][8 * u2 + 4 + 2 * e], sc[tb][8 * u2 + 4 + 2 * e + 1]);
                        u32x2 rr = __builtin_amdgcn_permlane32_swap(wd, ws, false, false);
                        paw[tb * 2 + u2][e] = rr[0];
                        paw[tb * 2 + u2][2 + e] = rr[1];
                    }
                }
            }
        } else {
            // NOSM: P words = bitcast scores (keeps QK^T live, zero softmax cost)
#pragma unroll
            for (int tb = 0; tb < 2; ++tb)
#pragma unroll
                for (int u2 = 0; u2 < 2; ++u2)
#pragma unroll
                    for (int e = 0; e < 2; ++e) {
                        paw[tb * 2 + u2][e]     = __builtin_bit_cast(unsigned, sc[tb][8 * u2 + 2 * e]);
                        paw[tb * 2 + u2][2 + e] = __builtin_bit_cast(unsigned, sc[tb][8 * u2 + 4 + 2 * e]);
                    }
        }

        __builtin_amdgcn_s_setprio(1);
#pragma unroll
        for (int dblk = 0; dblk < 2; ++dblk) {
            int row = dblk * 32 + q5;
            int rsw = (row & 7) << 4;
#pragma unroll
            for (int ks = 0; ks < 4; ++ks) {
                bf16x8 vf = *reinterpret_cast<const bf16x8*>(vls + row * 128 + ((ks * 32 + hi * 16) ^ rsw));
                oo[dblk] = __builtin_amdgcn_mfma_f32_32x32x16_bf16(
                    __builtin_bit_cast(bf16x8, paw[ks]), vf, oo[dblk], 0, 0, 0);
            }
        }
        __builtin_amdgcn_s_setprio(0);
        buf ^= 1;
    }

    float inv;
    if constexpr (SM) {
        u32x2 lsw = __builtin_amdgcn_permlane32_swap(__builtin_bit_cast(unsigned, lp),
                                                     __builtin_bit_cast(unsigned, lp), false, false);
        float lfull = __builtin_bit_cast(float, lsw[0]) + __builtin_bit_cast(float, lsw[1]);
        inv = 1.f / lfull;
    } else {
        inv = 1.f;
    }

    int b = bh >> 4, h = bh & 15;
#pragma unroll
    for (int r = 0; r < 16; ++r) {
        int qrel = (r & 3) + 8 * (r >> 2) + 4 * hi;
        float invr = SM ? __shfl(inv, qrel) : 1.f;
        int s = qr + qrel;
        size_t base = ((size_t)(b * SS + s)) * DMODEL + h * DHEAD;
        ctxo[base + q5]      = f2bf(oo[0][r] * invr);
        ctxo[base + 32 + q5] = f2bf(oo[1][r] * invr);
    }
}

// ---------------- V5 probe: register-direct K/V, no LDS, no barriers ----------------
// Same 32x32 in-reg-softmax core; each wave loads its own K/V frags from global
// (L2-resident). K prefetched 1 tile ahead into regs (T14); V loaded JIT.
__global__ __launch_bounds__(256) void attn_reg(
    const unsigned short* __restrict__ Qb, const unsigned short* __restrict__ Kb,
    const unsigned short* __restrict__ VTb, unsigned short* __restrict__ ctxo) {
    int bh = blockIdx.y;
    int q0 = blockIdx.x * 128;
    int t = threadIdx.x, wv = t >> 6, lane = t & 63;
    int q5 = lane & 31, hi = lane >> 5;
    const unsigned short* Qh  = Qb  + (size_t)bh * SS * DHEAD;
    const unsigned short* Kh  = Kb  + (size_t)bh * SS * DHEAD;
    const unsigned short* VTh = VTb + (size_t)bh * DHEAD * SS;
    int qr = q0 + wv * 32;

    bf16x8 qf[4];
#pragma unroll
    for (int m = 0; m < 4; ++m)
        qf[m] = ld8(&Qh[(size_t)(qr + q5) * DHEAD + m * 16 + hi * 8]);

    f32x16 oo[2];
    oo[0] = (f32x16)0.f; oo[1] = (f32x16)0.f;
    float lp = 0.f, mrun = 0.f;

    bf16x8 kpre[2][4];
#pragma unroll
    for (int tb = 0; tb < 2; ++tb)
#pragma unroll
        for (int m = 0; m < 4; ++m)
            kpre[tb][m] = ld8(&Kh[(size_t)(tb * 32 + q5) * DHEAD + m * 16 + hi * 8]);

    for (int t0 = 0; t0 < SS; t0 += 64) {
        // QK^T from prefetched K regs
        f32x16 sc[2];
        __builtin_amdgcn_s_setprio(1);
#pragma unroll
        for (int tb = 0; tb < 2; ++tb) {
            f32x16 s = (f32x16)0.f;
#pragma unroll
            for (int m = 0; m < 4; ++m)
                s = __builtin_amdgcn_mfma_f32_32x32x16_bf16(kpre[tb][m], qf[m], s, 0, 0, 0);
            sc[tb] = s;
        }
        __builtin_amdgcn_s_setprio(0);

        // issue V loads (JIT) and next-tile K prefetch; latency hides under softmax
        bf16x8 vf[2][4];
#pragma unroll
        for (int dblk = 0; dblk < 2; ++dblk)
#pragma unroll
            for (int ks = 0; ks < 4; ++ks)
                vf[dblk][ks] = ld8(&VTh[(size_t)(dblk * 32 + q5) * SS + t0 + ks * 16 + hi * 8]);
        if (t0 + 64 < SS) {
#pragma unroll
            for (int tb = 0; tb < 2; ++tb)
#pragma unroll
                for (int m = 0; m < 4; ++m)
                    kpre[tb][m] = ld8(&Kh[(size_t)(t0 + 64 + tb * 32 + q5) * DHEAD + m * 16 + hi * 8]);
        }

        float lm = sc[0][0];
#pragma unroll
        for (int r = 1; r < 16; ++r) lm = fmaxf(lm, sc[0][r]);
#pragma unroll
        for (int r = 0; r < 16; ++r) lm = fmaxf(lm, sc[1][r]);
        u32x2 sw = __builtin_amdgcn_permlane32_swap(__builtin_bit_cast(unsigned, lm),
                                                    __builtin_bit_cast(unsigned, lm), false, false);
        float rowmax = fmaxf(__builtin_bit_cast(float, sw[0]), __builtin_bit_cast(float, sw[1]));

        if (__any(rowmax > mrun + 8.f)) {
            float mn = fmaxf(mrun, rowmax);
            float al = exp2f((mrun - mn) * LOG2E);
            mrun = mn;
            lp *= al;
#pragma unroll
            for (int r = 0; r < 16; ++r) {
                float alr = __shfl(al, (r & 3) + 8 * (r >> 2) + 4 * hi);
                oo[0][r] *= alr; oo[1][r] *= alr;
            }
        }

        float ml = mrun * LOG2E;
        float ps = 0.f;
#pragma unroll
        for (int tb = 0; tb < 2; ++tb)
#pragma unroll
            for (int r = 0; r < 16; ++r) {
                float p = exp2f(__builtin_fmaf(sc[tb][r], LOG2E, -ml));
                sc[tb][r] = p;
                ps += p;
            }
        lp += ps;

        u32x4 paw[4];
#pragma unroll
        for (int tb = 0; tb < 2; ++tb)
#pragma unroll
            for (int u2 = 0; u2 < 2; ++u2)
#pragma unroll
                for (int e = 0; e < 2; ++e) {
                    unsigned wd = cvt_pk_bf16(sc[tb][8 * u2 + 2 * e], sc[tb][8 * u2 + 2 * e + 1]);
                    unsigned ws = cvt_pk_bf16(sc[tb][8 * u2 + 4 + 2 * e], sc[tb][8 * u2 + 4 + 2 * e + 1]);
                    u32x2 rr = __builtin_amdgcn_permlane32_swap(wd, ws, false, false);
                    paw[tb * 2 + u2][e] = rr[0];
                    paw[tb * 2 + u2][2 + e] = rr[1];
                }

        __builtin_amdgcn_s_setprio(1);
#pragma unroll
        for (int dblk = 0; dblk < 2; ++dblk)
#pragma unroll
            for (int ks = 0; ks < 4; ++ks)
                oo[dblk] = __builtin_amdgcn_mfma_f32_32x32x16_bf16(
                    __builtin_bit_cast(bf16x8, paw[ks]), vf[dblk][ks], oo[dblk], 0, 0, 0);
        __builtin_amdgcn_s_setprio(0);
    }

    u32x2 lsw = __builtin_amdgcn_permlane32_swap(__builtin_bit_cast(unsigned, lp),
                                                 __builtin_bit_cast(unsigned, lp), false, false);
    float lfull = __builtin_bit_cast(float, lsw[0]) + __builtin_bit_cast(float, lsw[1]);
    float inv = 1.f / lfull;

    int b = bh >> 4, h = bh & 15;
#pragma unroll
    for (int r = 0; r < 16; ++r) {
        int qrel = (r & 3) + 8 * (r >> 2) + 4 * hi;
        float invr = __shfl(inv, qrel);
        int s = qr + qrel;
        size_t base = ((size_t)(b * SS + s)) * DMODEL + h * DHEAD;
        ctxo[base + q5]      = f2bf(oo[0][r] * invr);
        ctxo[base + 32 + q5] = f2bf(oo[1][r] * invr);
    }
}

// ---------------- output projection -> fp32 proj (128x64 tile, syncthreads) ----------------
__global__ __launch_bounds__(256) void gemm_proj(
    const unsigned short* __restrict__ ctxb, const unsigned short* __restrict__ Wdb,
    const float* __restrict__ bd, float* __restrict__ proj) {
    __shared__ unsigned short Als[4096];   // [kb4][128][8]
    __shared__ unsigned short Bls[2048];   // [kb4][64][8]
    int m0 = blockIdx.y * 128, n0 = blockIdx.x * 64;
    int t = threadIdx.x, wv = t >> 6, lane = t & 63;
    int lrow = lane & 15, lgrp = lane >> 4;
    int srow = t & 127, skb = t >> 7;

    const unsigned short* Ag = ctxb + (size_t)(m0 + srow) * DMODEL + skb * 8;
    const unsigned short* Bg = Wdb  + (size_t)(n0 + (t & 63)) * DMODEL + wv * 8;

    f32x4 acc[2][4];
#pragma unroll
    for (int mi = 0; mi < 2; ++mi)
#pragma unroll
        for (int ni = 0; ni < 4; ++ni) acc[mi][ni] = (f32x4){0.f, 0.f, 0.f, 0.f};

    for (int k0 = 0; k0 < DMODEL; k0 += 32) {
#pragma unroll
        for (int i = 0; i < 2; ++i)
            gload_lds16(Ag + k0 + i * 16, Als + i * 2048 + wv * 512);
        gload_lds16(Bg + k0, Bls + wv * 512);
        __syncthreads();

        bf16x8 af[2], bfr[4];
#pragma unroll
        for (int i = 0; i < 2; ++i)
            af[i] = ld8(&Als[lgrp * 1024 + (wv * 32 + i * 16 + lrow) * 8]);
#pragma unroll
        for (int i = 0; i < 4; ++i)
            bfr[i] = ld8(&Bls[lgrp * 512 + (i * 16 + lrow) * 8]);
#pragma unroll
        for (int mi = 0; mi < 2; ++mi)
#pragma unroll
            for (int ni = 0; ni < 4; ++ni)
                acc[mi][ni] = __builtin_amdgcn_mfma_f32_16x16x32_bf16(af[mi], bfr[ni], acc[mi][ni], 0, 0, 0);
        __syncthreads();
    }

#pragma unroll
    for (int mi = 0; mi < 2; ++mi)
#pragma unroll
        for (int ni = 0; ni < 4; ++ni) {
            int col = n0 + ni * 16 + lrow;
            float bi = bd[col];
#pragma unroll
            for (int r = 0; r < 4; ++r) {
                int row = m0 + wv * 32 + mi * 16 + lgrp * 4 + r;
                proj[(size_t)row * DMODEL + col] = acc[mi][ni][r] + bi;
            }
        }
}

// ---------------- LayerNorm over D=1024 ----------------
__global__ __launch_bounds__(256) void ln_kernel(const float* __restrict__ proj,
                                                 const float* __restrict__ g,
                                                 const float* __restrict__ bv,
                                                 float* __restrict__ out) {
    int row = blockIdx.x, t = threadIdx.x;
    float4 v = reinterpret_cast<const float4*>(proj + (size_t)row * DMODEL)[t];
    float s  = v.x + v.y + v.z + v.w;
    float s2 = v.x * v.x + v.y * v.y + v.z * v.z + v.w * v.w;
#pragma unroll
    for (int m = 1; m < 64; m <<= 1) { s += __shfl_xor(s, m); s2 += __shfl_xor(s2, m); }
    __shared__ float red[8];
    int wv = t >> 6, lane = t & 63;
    if (lane == 0) { red[wv] = s; red[wv + 4] = s2; }
    __syncthreads();
    s  = red[0] + red[1] + red[2] + red[3];
    s2 = red[4] + red[5] + red[6] + red[7];
    float mu  = s * (1.f / 1024.f);
    float var = s2 * (1.f / 1024.f) - mu * mu;
    float inv = rsqrtf(var + 1e-12f);
    float4 gv = reinterpret_cast<const float4*>(g)[t];
    float4 bb = reinterpret_cast<const float4*>(bv)[t];
    float4 ov;
    ov.x = (v.x - mu) * inv * gv.x + bb.x;
    ov.y = (v.y - mu) * inv * gv.y + bb.y;
    ov.z = (v.z - mu) * inv * gv.z + bb.z;
    ov.w = (v.w - mu) * inv * gv.w + bb.w;
    reinterpret_cast<float4*>(out + (size_t)row * DMODEL)[t] = ov;
}

extern "C" void kernel_launch(void* const* d_in, const int* in_sizes, int n_in,
                              void* d_out, int out_size, void* d_ws, size_t ws_size,
                              hipStream_t stream) {
    const float* x   = (const float*)d_in[0];
    const float* Wq  = (const float*)d_in[1];
    const float* bq  = (const float*)d_in[2];
    const float* Wk  = (const float*)d_in[3];
    const float* bk  = (const float*)d_in[4];
    const float* Wv  = (const float*)d_in[5];
    const float* bv  = (const float*)d_in[6];
    const float* Wd  = (const float*)d_in[7];
    const float* bd  = (const float*)d_in[8];
    const float* lng = (const float*)d_in[9];
    const float* lnb = (const float*)d_in[10];

    char* ws = (char*)d_ws;
    unsigned short* xb   = (unsigned short*)(ws);                    // 8 MB
    unsigned short* Wqb  = (unsigned short*)(ws + (8u  << 20));      // 2 MB each
    unsigned short* Wkb  = (unsigned short*)(ws + (10u << 20));
    unsigned short* Wvb  = (unsigned short*)(ws + (12u << 20));
    unsigned short* Wdb  = (unsigned short*)(ws + (14u << 20));
    unsigned short* Qb   = (unsigned short*)(ws + (16u << 20));      // 8 MB
    unsigned short* Kb   = (unsigned short*)(ws + (24u << 20));      // 8 MB
    unsigned short* VTb  = (unsigned short*)(ws + (32u << 20));      // 8 MB
    unsigned short* ctxb = (unsigned short*)(ws + (40u << 20));      // 8 MB
    float* proj = (float*)(ws + (16u << 20));  // 16 MB, aliases Q/K (dead after attention)

    // ---- real pipeline (identical to R7) ----
    cvt_kernel<<<4096, 256, 0, stream>>>(x, xb, 1048576);
    cvtw_kernel<<<dim3(1024, 4), 256, 0, stream>>>(Wq, Wk, Wv, Wd, Wqb, Wkb, Wvb, Wdb);
    gemm_qkv<<<dim3(8, 32, 3), 256, 0, stream>>>(xb, Wqb, Wkb, Wvb, bq, bk, bv, Qb, Kb, VTb);
    attn_abl<0><<<dim3(16, 32), 256, 0, stream>>>(Qb, Kb, VTb, ctxb);
    gemm_proj<<<dim3(16, 32), 256, 0, stream>>>(ctxb, Wdb, bd, proj);
    ln_kernel<<<4096, 256, 0, stream>>>(proj, lng, lnb, (float*)d_out);

    // ---- ablation probes (scratch output = ctxb, already consumed) ----
    attn_abl<1><<<dim3(16, 32), 256, 0, stream>>>(Qb, Kb, VTb, ctxb);   // NOSTAGE
    attn_abl<2><<<dim3(16, 32), 256, 0, stream>>>(Qb, Kb, VTb, ctxb);   // NOSM
    attn_abl<4><<<dim3(16, 32), 256, 0, stream>>>(Qb, Kb, VTb, ctxb);   // floor
    attn_reg<<<dim3(16, 32), 256, 0, stream>>>(Qb, Kb, VTb, ctxb);      // V5 probe
}

// Round 9
// 182.631 us; speedup vs baseline: 2.3537x; 2.3537x over previous
//
#include <hip/hip_runtime.h>

#define HD 16
#define DHEAD 64
#define DMODEL 1024
#define BB 2
#define SS 2048
#define MTOT (BB*SS)   // 4096
#define LOG2E 1.44269504f

typedef float f32x4 __attribute__((ext_vector_type(4)));
typedef float f32x16 __attribute__((ext_vector_type(16)));
typedef __bf16 bf16x8 __attribute__((ext_vector_type(8)));
typedef unsigned short u16x8 __attribute__((ext_vector_type(8)));
typedef unsigned int u32x2 __attribute__((ext_vector_type(2)));
typedef unsigned int u32x4 __attribute__((ext_vector_type(4)));

__device__ __forceinline__ unsigned short f2bf(float f) {
    unsigned int u = __builtin_bit_cast(unsigned int, f);
    unsigned int r = (u + 0x7fffu + ((u >> 16) & 1u)) >> 16;   // RNE
    return (unsigned short)r;
}

__device__ __forceinline__ bf16x8 ld8(const unsigned short* p) {
    u16x8 v = *reinterpret_cast<const u16x8*>(p);
    return __builtin_bit_cast(bf16x8, v);
}

__device__ __forceinline__ void gload_lds16(const unsigned short* g, unsigned short* l) {
    __builtin_amdgcn_global_load_lds(
        (const __attribute__((address_space(1))) void*)g,
        (__attribute__((address_space(3))) void*)l, 16, 0, 0);
}

__device__ __forceinline__ void gload_lds16b(const char* g, char* l) {
    __builtin_amdgcn_global_load_lds(
        (const __attribute__((address_space(1))) void*)g,
        (__attribute__((address_space(3))) void*)l, 16, 0, 0);
}

__device__ __forceinline__ unsigned cvt_pk_bf16(float lo, float hi) {
    unsigned r;
    asm("v_cvt_pk_bf16_f32 %0, %1, %2" : "=v"(r) : "v"(lo), "v"(hi));
    return r;
}

// ---------------- fp32 -> bf16 converts (one launch: 4 weights + x) ----------------
__global__ __launch_bounds__(256) void cvt_all(
    const float* __restrict__ x,
    const float* __restrict__ w0, const float* __restrict__ w1,
    const float* __restrict__ w2, const float* __restrict__ w3,
    unsigned short* __restrict__ xb,
    unsigned short* __restrict__ o0, unsigned short* __restrict__ o1,
    unsigned short* __restrict__ o2, unsigned short* __restrict__ o3) {
    int y = blockIdx.y;
    const float* in;
    unsigned short* out;
    int idx;
    if (y < 4) {
        in  = (y == 0) ? w0 : (y == 1) ? w1 : (y == 2) ? w2 : w3;
        out = (y == 0) ? o0 : (y == 1) ? o1 : (y == 2) ? o2 : o3;
        idx = blockIdx.x * 256 + threadIdx.x;
    } else {
        in  = x;
        out = xb;
        idx = ((y - 4) * 1024 + blockIdx.x) * 256 + threadIdx.x;
    }
    float4 v = reinterpret_cast<const float4*>(in)[idx];
    ushort4 o;
    o.x = f2bf(v.x); o.y = f2bf(v.y); o.z = f2bf(v.z); o.w = f2bf(v.w);
    reinterpret_cast<ushort4*>(out)[idx] = o;
}

// ---------------- GEMM core: C[128x128] = A[M,K] * B[N,K]^T (single-buf, syncthreads) ----------------
__device__ __forceinline__ void gemm_core(const unsigned short* __restrict__ A,
                                          const unsigned short* __restrict__ Bm,
                                          unsigned short* Als, unsigned short* Bls,
                                          int m0, int n0, int K, f32x4 acc[4][4]) {
    int t    = threadIdx.x;
    int wv   = t >> 6, lane = t & 63;
    int lrow = lane & 15, lgrp = lane >> 4;
    int wr   = wv >> 1, wc = wv & 1;
    int srow = t & 127, skb = t >> 7;

    const unsigned short* Ag = A  + (size_t)(m0 + srow) * K + skb * 8;
    const unsigned short* Bg = Bm + (size_t)(n0 + srow) * K + skb * 8;

    for (int k0 = 0; k0 < K; k0 += 32) {
#pragma unroll
        for (int i = 0; i < 2; ++i) {
            gload_lds16(Ag + k0 + i * 16, Als + i * 2048 + wv * 512);
            gload_lds16(Bg + k0 + i * 16, Bls + i * 2048 + wv * 512);
        }
        __syncthreads();

        bf16x8 af[4], bfr[4];
#pragma unroll
        for (int i = 0; i < 4; ++i) {
            af[i]  = ld8(&Als[lgrp * 1024 + (wr * 64 + i * 16 + lrow) * 8]);
            bfr[i] = ld8(&Bls[lgrp * 1024 + (wc * 64 + i * 16 + lrow) * 8]);
        }
#pragma unroll
        for (int mi = 0; mi < 4; ++mi)
#pragma unroll
            for (int ni = 0; ni < 4; ++ni)
                acc[mi][ni] = __builtin_amdgcn_mfma_f32_16x16x32_bf16(af[mi], bfr[ni], acc[mi][ni], 0, 0, 0);
        __syncthreads();
    }
}

// ---------------- QKV projection (grid.z selects Q/K/V) ----------------
__global__ __launch_bounds__(256) void gemm_qkv(
    const unsigned short* __restrict__ xb,
    const unsigned short* __restrict__ Wqb, const unsigned short* __restrict__ Wkb,
    const unsigned short* __restrict__ Wvb,
    const float* __restrict__ bq, const float* __restrict__ bk, const float* __restrict__ bv,
    unsigned short* __restrict__ Qo, unsigned short* __restrict__ Ko, unsigned short* __restrict__ VTo) {
    __shared__ unsigned short Als[4096], Bls[4096];
    int z = blockIdx.z;
    const unsigned short* Bm = (z == 0) ? Wqb : (z == 1) ? Wkb : Wvb;
    const float* bias = (z == 0) ? bq : (z == 1) ? bk : bv;
    int m0 = blockIdx.y * 128, n0 = blockIdx.x * 128;

    f32x4 acc[4][4];
#pragma unroll
    for (int mi = 0; mi < 4; ++mi)
#pragma unroll
        for (int ni = 0; ni < 4; ++ni) acc[mi][ni] = (f32x4){0.f, 0.f, 0.f, 0.f};

    gemm_core(xb, Bm, Als, Bls, m0, n0, DMODEL, acc);

    int t = threadIdx.x, wv = t >> 6, lane = t & 63;
    int lrow = lane & 15, lgrp = lane >> 4;
    int wr = wv >> 1, wc = wv & 1;
    // Q: fold 1/sqrt(64) AND log2(e) so attention exp is exp2 of a plain subtract
    float scale = (z == 0) ? (0.125f * LOG2E) : 1.0f;

#pragma unroll
    for (int mi = 0; mi < 4; ++mi) {
#pragma unroll
        for (int ni = 0; ni < 4; ++ni) {
            int col = n0 + wc * 64 + ni * 16 + lrow;
            int h = col >> 6, dh = col & 63;
            float bi = bias[col];
            if (z == 2) {
                int row0 = m0 + wr * 64 + mi * 16 + lgrp * 4;
                int b = row0 >> 11, s0 = row0 & 2047;
                ushort4 pk;
                pk.x = f2bf(acc[mi][ni][0] + bi);
                pk.y = f2bf(acc[mi][ni][1] + bi);
                pk.z = f2bf(acc[mi][ni][2] + bi);
                pk.w = f2bf(acc[mi][ni][3] + bi);
                *reinterpret_cast<ushort4*>(&VTo[((size_t)((b * HD + h) * DHEAD + dh)) * SS + s0]) = pk;
            } else {
#pragma unroll
                for (int r = 0; r < 4; ++r) {
                    int row = m0 + wr * 64 + mi * 16 + lgrp * 4 + r;
                    int b = row >> 11, s = row & 2047;
                    unsigned short v16 = f2bf((acc[mi][ni][r] + bi) * scale);
                    unsigned short* o = (z == 0) ? Qo : Ko;                           // [bh][s][dh]
                    o[((size_t)((b * HD + h) * SS + s)) * DHEAD + dh] = v16;
                }
            }
        }
    }
}

// ---------------- flash attention: 32x32 MFMA, in-reg softmax, XCD-swizzled ----------------
// Chunked XCD remap: each XCD owns 64 consecutive wgids = 4 whole heads, so a
// head's K/V (512KB) is fetched into exactly one XCD's L2 and reused by its 16
// q-blocks. KVBLK=128 staged per barrier pair (two 64-halves computed per stage).
// Row-sums via mfma(P, ones) into ls (o-layout) -> no psum chain, no end shuffles.
__global__ __launch_bounds__(256, 2) void attn_kernel(
    const unsigned short* __restrict__ Qb, const unsigned short* __restrict__ Kb,
    const unsigned short* __restrict__ VTb, unsigned short* __restrict__ ctxo) {
    __shared__ unsigned short Kls[2][8192];   // [128 t][64 dh] bf16, swizzled (16KB/buf)
    __shared__ unsigned short Vls[2][8192];   // [64 d][128 t]  bf16, swizzled
    int L = blockIdx.x + (int)gridDim.x * blockIdx.y;   // 0..511
    int wg = (L & 7) * 64 + (L >> 3);                   // bijective XCD-chunked remap
    int q0 = (wg & 15) * 128;
    int bh = wg >> 4;
    int t = threadIdx.x, wv = t >> 6, lane = t & 63;
    int q5 = lane & 31, hi = lane >> 5;
    const unsigned short* Qh  = Qb  + (size_t)bh * SS * DHEAD;
    const char* Khc  = (const char*)(Kb  + (size_t)bh * SS * DHEAD);
    const char* VThc = (const char*)(VTb + (size_t)bh * DHEAD * SS);
    int qr = q0 + wv * 32;

    bf16x8 qf[4];
#pragma unroll
    for (int m = 0; m < 4; ++m)
        qf[m] = ld8(&Qh[(size_t)(qr + q5) * DHEAD + m * 16 + hi * 8]);

    const __bf16 one_bf = (__bf16)1.0f;
    bf16x8 ones8 = {one_bf, one_bf, one_bf, one_bf, one_bf, one_bf, one_bf, one_bf};

    f32x16 oo[2];
    oo[0] = (f32x16)0.f; oo[1] = (f32x16)0.f;
    f32x16 ls = (f32x16)0.f;   // row-sums, o-layout, via mfma(P, ones)
    float mrun = 0.f;          // log2-units (Q pre-scaled by LOG2E); defer-max THR=8

    auto stage = [&](int buf, int t0) {
#pragma unroll
        for (int i = 0; i < 4; ++i) {
            int c = t + 256 * i;
            int kr = c >> 3, kc = ((c & 7) << 4) ^ ((kr & 7) << 4);
            gload_lds16b(Khc + (size_t)(t0 + kr) * 128 + kc, (char*)&Kls[buf][0] + c * 16);
        }
#pragma unroll
        for (int i = 0; i < 4; ++i) {
            int c = t + 256 * i;
            int vr = c >> 4, vc = ((c & 15) << 4) ^ ((vr & 7) << 4);
            gload_lds16b(VThc + ((size_t)vr * SS + t0) * 2 + vc, (char*)&Vls[buf][0] + c * 16);
        }
    };

    stage(0, 0);
    int buf = 0;

    for (int t0 = 0; t0 < SS; t0 += 128) {
        __builtin_amdgcn_s_barrier();          // all waves done reading buf^1
        if (t0 + 128 < SS) {
            stage(buf ^ 1, t0 + 128);
            asm volatile("s_waitcnt vmcnt(8)" ::: "memory");   // own current-tile loads done
        } else {
            asm volatile("s_waitcnt vmcnt(0)" ::: "memory");
        }
        __builtin_amdgcn_sched_barrier(0);
        __builtin_amdgcn_s_barrier();          // all waves' current-tile loads done
        __builtin_amdgcn_sched_barrier(0);

        const char* kls = (const char*)&Kls[buf][0];
        const char* vls = (const char*)&Vls[buf][0];

#pragma unroll
        for (int half = 0; half < 2; ++half) {
            // QK^T for this half's 64 t
            f32x16 sc[2];
            __builtin_amdgcn_s_setprio(1);
#pragma unroll
            for (int tb = 0; tb < 2; ++tb) {
                int row = (half * 2 + tb) * 32 + q5;
                int rsw = (row & 7) << 4;
                f32x16 s = (f32x16)0.f;
#pragma unroll
                for (int m = 0; m < 4; ++m) {
                    bf16x8 kf = *reinterpret_cast<const bf16x8*>(kls + row * 128 + ((m * 32 + hi * 16) ^ rsw));
                    s = __builtin_amdgcn_mfma_f32_32x32x16_bf16(kf, qf[m], s, 0, 0, 0);
                }
                sc[tb] = s;
            }
            __builtin_amdgcn_s_setprio(0);

            // balanced max tree (depth 5) over this lane's 32 scores -> guard
            float mx[16];
#pragma unroll
            for (int r = 0; r < 16; ++r) mx[r] = fmaxf(sc[0][r], sc[1][r]);
#pragma unroll
            for (int st = 8; st; st >>= 1)
#pragma unroll
                for (int r = 0; r < st; ++r) mx[r] = fmaxf(mx[r], mx[r + st]);
            float lm = mx[0];

            if (__any(lm > mrun + 8.f)) {      // rare: rescale oo, ls
                u32x2 sw = __builtin_amdgcn_permlane32_swap(__builtin_bit_cast(unsigned, lm),
                                                            __builtin_bit_cast(unsigned, lm), false, false);
                float rowmax = fmaxf(__builtin_bit_cast(float, sw[0]), __builtin_bit_cast(float, sw[1]));
                float mn = fmaxf(mrun, rowmax);
                float al = exp2f(mrun - mn);
                mrun = mn;
#pragma unroll
                for (int r = 0; r < 16; ++r) {
                    float alr = __shfl(al, (r & 3) + 8 * (r >> 2) + 4 * hi);
                    oo[0][r] *= alr; oo[1][r] *= alr; ls[r] *= alr;
                }
            }

            // exp (scores already in log2 domain)
#pragma unroll
            for (int tb = 0; tb < 2; ++tb)
#pragma unroll
                for (int r = 0; r < 16; ++r)
                    sc[tb][r] = exp2f(sc[tb][r] - mrun);

            // P -> bf16 A-frags: 16 cvt_pk + 8 permlane32_swap
            u32x4 paw[4];
#pragma unroll
            for (int tb = 0; tb < 2; ++tb)
#pragma unroll
                for (int u2 = 0; u2 < 2; ++u2)
#pragma unroll
                    for (int e = 0; e < 2; ++e) {
                        unsigned wd = cvt_pk_bf16(sc[tb][8 * u2 + 2 * e], sc[tb][8 * u2 + 2 * e + 1]);
                        unsigned ws = cvt_pk_bf16(sc[tb][8 * u2 + 4 + 2 * e], sc[tb][8 * u2 + 4 + 2 * e + 1]);
                        u32x2 rr = __builtin_amdgcn_permlane32_swap(wd, ws, false, false);
                        paw[tb * 2 + u2][e] = rr[0];
                        paw[tb * 2 + u2][2 + e] = rr[1];
                    }

            // PV + ones-MFMA row-sums
            __builtin_amdgcn_s_setprio(1);
#pragma unroll
            for (int dblk = 0; dblk < 2; ++dblk) {
                int row = dblk * 32 + q5;
                int rsw = (row & 7) << 4;
#pragma unroll
                for (int ks = 0; ks < 4; ++ks) {
                    bf16x8 vf = *reinterpret_cast<const bf16x8*>(
                        vls + row * 256 + ((half * 128 + ks * 32 + hi * 16) ^ rsw));
                    oo[dblk] = __builtin_amdgcn_mfma_f32_32x32x16_bf16(
                        __builtin_bit_cast(bf16x8, paw[ks]), vf, oo[dblk], 0, 0, 0);
                }
            }
#pragma unroll
            for (int ks = 0; ks < 4; ++ks)
                ls = __builtin_amdgcn_mfma_f32_32x32x16_bf16(
                    __builtin_bit_cast(bf16x8, paw[ks]), ones8, ls, 0, 0, 0);
            __builtin_amdgcn_s_setprio(0);
        }
        buf ^= 1;
    }

    int b = bh >> 4, h = bh & 15;
#pragma unroll
    for (int r = 0; r < 16; ++r) {
        float invr = 1.f / ls[r];              // row-sum already in o-layout
        int qrel = (r & 3) + 8 * (r >> 2) + 4 * hi;
        int s = qr + qrel;
        size_t base = ((size_t)(b * SS + s)) * DMODEL + h * DHEAD;
        ctxo[base + q5]      = f2bf(oo[0][r] * invr);
        ctxo[base + 32 + q5] = f2bf(oo[1][r] * invr);
    }
}

// ---------------- output projection -> fp32 proj (128x64 tile, syncthreads) ----------------
__global__ __launch_bounds__(256) void gemm_proj(
    const unsigned short* __restrict__ ctxb, const unsigned short* __restrict__ Wdb,
    const float* __restrict__ bd, float* __restrict__ proj) {
    __shared__ unsigned short Als[4096];   // [kb4][128][8]
    __shared__ unsigned short Bls[2048];   // [kb4][64][8]
    int m0 = blockIdx.y * 128, n0 = blockIdx.x * 64;
    int t = threadIdx.x, wv = t >> 6, lane = t & 63;
    int lrow = lane & 15, lgrp = lane >> 4;
    int srow = t & 127, skb = t >> 7;

    const unsigned short* Ag = ctxb + (size_t)(m0 + srow) * DMODEL + skb * 8;
    const unsigned short* Bg = Wdb  + (size_t)(n0 + (t & 63)) * DMODEL + wv * 8;

    f32x4 acc[2][4];
#pragma unroll
    for (int mi = 0; mi < 2; ++mi)
#pragma unroll
        for (int ni = 0; ni < 4; ++ni) acc[mi][ni] = (f32x4){0.f, 0.f, 0.f, 0.f};

    for (int k0 = 0; k0 < DMODEL; k0 += 32) {
#pragma unroll
        for (int i = 0; i < 2; ++i)
            gload_lds16(Ag + k0 + i * 16, Als + i * 2048 + wv * 512);
        gload_lds16(Bg + k0, Bls + wv * 512);
        __syncthreads();

        bf16x8 af[2], bfr[4];
#pragma unroll
        for (int i = 0; i < 2; ++i)
            af[i] = ld8(&Als[lgrp * 1024 + (wv * 32 + i * 16 + lrow) * 8]);
#pragma unroll
        for (int i = 0; i < 4; ++i)
            bfr[i] = ld8(&Bls[lgrp * 512 + (i * 16 + lrow) * 8]);
#pragma unroll
        for (int mi = 0; mi < 2; ++mi)
#pragma unroll
            for (int ni = 0; ni < 4; ++ni)
                acc[mi][ni] = __builtin_amdgcn_mfma_f32_16x16x32_bf16(af[mi], bfr[ni], acc[mi][ni], 0, 0, 0);
        __syncthreads();
    }

#pragma unroll
    for (int mi = 0; mi < 2; ++mi)
#pragma unroll
        for (int ni = 0; ni < 4; ++ni) {
            int col = n0 + ni * 16 + lrow;
            float bi = bd[col];
#pragma unroll
            for (int r = 0; r < 4; ++r) {
                int row = m0 + wv * 32 + mi * 16 + lgrp * 4 + r;
                proj[(size_t)row * DMODEL + col] = acc[mi][ni][r] + bi;
            }
        }
}

// ---------------- LayerNorm over D=1024 ----------------
__global__ __launch_bounds__(256) void ln_kernel(const float* __restrict__ proj,
                                                 const float* __restrict__ g,
                                                 const float* __restrict__ bv,
                                                 float* __restrict__ out) {
    int row = blockIdx.x, t = threadIdx.x;
    float4 v = reinterpret_cast<const float4*>(proj + (size_t)row * DMODEL)[t];
    float s  = v.x + v.y + v.z + v.w;
    float s2 = v.x * v.x + v.y * v.y + v.z * v.z + v.w * v.w;
#pragma unroll
    for (int m = 1; m < 64; m <<= 1) { s += __shfl_xor(s, m); s2 += __shfl_xor(s2, m); }
    __shared__ float red[8];
    int wv = t >> 6, lane = t & 63;
    if (lane == 0) { red[wv] = s; red[wv + 4] = s2; }
    __syncthreads();
    s  = red[0] + red[1] + red[2] + red[3];
    s2 = red[4] + red[5] + red[6] + red[7];
    float mu  = s * (1.f / 1024.f);
    float var = s2 * (1.f / 1024.f) - mu * mu;
    float inv = rsqrtf(var + 1e-12f);
    float4 gv = reinterpret_cast<const float4*>(g)[t];
    float4 bb = reinterpret_cast<const float4*>(bv)[t];
    float4 ov;
    ov.x = (v.x - mu) * inv * gv.x + bb.x;
    ov.y = (v.y - mu) * inv * gv.y + bb.y;
    ov.z = (v.z - mu) * inv * gv.z + bb.z;
    ov.w = (v.w - mu) * inv * gv.w + bb.w;
    reinterpret_cast<float4*>(out + (size_t)row * DMODEL)[t] = ov;
}

extern "C" void kernel_launch(void* const* d_in, const int* in_sizes, int n_in,
                              void* d_out, int out_size, void* d_ws, size_t ws_size,
                              hipStream_t stream) {
    const float* x   = (const float*)d_in[0];
    const float* Wq  = (const float*)d_in[1];
    const float* bq  = (const float*)d_in[2];
    const float* Wk  = (const float*)d_in[3];
    const float* bk  = (const float*)d_in[4];
    const float* Wv  = (const float*)d_in[5];
    const float* bv  = (const float*)d_in[6];
    const float* Wd  = (const float*)d_in[7];
    const float* bd  = (const float*)d_in[8];
    const float* lng = (const float*)d_in[9];
    const float* lnb = (const float*)d_in[10];

    char* ws = (char*)d_ws;
    unsigned short* xb   = (unsigned short*)(ws);                    // 8 MB
    unsigned short* Wqb  = (unsigned short*)(ws + (8u  << 20));      // 2 MB each
    unsigned short* Wkb  = (unsigned short*)(ws + (10u << 20));
    unsigned short* Wvb  = (unsigned short*)(ws + (12u << 20));
    unsigned short* Wdb  = (unsigned short*)(ws + (14u << 20));
    unsigned short* Qb   = (unsigned short*)(ws + (16u << 20));      // 8 MB
    unsigned short* Kb   = (unsigned short*)(ws + (24u << 20));      // 8 MB
    unsigned short* VTb  = (unsigned short*)(ws + (32u << 20));      // 8 MB
    unsigned short* ctxb = (unsigned short*)(ws + (40u << 20));      // 8 MB
    float* proj = (float*)(ws + (16u << 20));  // 16 MB, aliases Q/K (dead after attention)

    cvt_all<<<dim3(1024, 8), 256, 0, stream>>>(x, Wq, Wk, Wv, Wd, xb, Wqb, Wkb, Wvb, Wdb);
    gemm_qkv<<<dim3(8, 32, 3), 256, 0, stream>>>(xb, Wqb, Wkb, Wvb, bq, bk, bv, Qb, Kb, VTb);
    attn_kernel<<<dim3(16, 32), 256, 0, stream>>>(Qb, Kb, VTb, ctxb);
    gemm_proj<<<dim3(16, 32), 256, 0, stream>>>(ctxb, Wdb, bd, proj);
    ln_kernel<<<4096, 256, 0, stream>>>(proj, lng, lnb, (float*)d_out);
}

// Round 10
// 140.360 us; speedup vs baseline: 3.0625x; 1.3012x over previous
//
#include <hip/hip_runtime.h>

#define HD 16
#define DHEAD 64
#define DMODEL 1024
#define BB 2
#define SS 2048
#define MTOT (BB*SS)   // 4096
#define LOG2E 1.44269504f

typedef float f32x4 __attribute__((ext_vector_type(4)));
typedef float f32x16 __attribute__((ext_vector_type(16)));
typedef __bf16 bf16x8 __attribute__((ext_vector_type(8)));
typedef unsigned short u16x8 __attribute__((ext_vector_type(8)));
typedef unsigned int u32x2 __attribute__((ext_vector_type(2)));
typedef unsigned int u32x4 __attribute__((ext_vector_type(4)));

__device__ __forceinline__ unsigned short f2bf(float f) {
    unsigned int u = __builtin_bit_cast(unsigned int, f);
    unsigned int r = (u + 0x7fffu + ((u >> 16) & 1u)) >> 16;   // RNE
    return (unsigned short)r;
}

__device__ __forceinline__ bf16x8 ld8(const unsigned short* p) {
    u16x8 v = *reinterpret_cast<const u16x8*>(p);
    return __builtin_bit_cast(bf16x8, v);
}

__device__ __forceinline__ void gload_lds16b(const char* g, char* l) {
    __builtin_amdgcn_global_load_lds(
        (const __attribute__((address_space(1))) void*)g,
        (__attribute__((address_space(3))) void*)l, 16, 0, 0);
}

__device__ __forceinline__ unsigned cvt_pk_bf16(float lo, float hi) {
    unsigned r;
    asm("v_cvt_pk_bf16_f32 %0, %1, %2" : "=v"(r) : "v"(lo), "v"(hi));
    return r;
}

// ---------------- fp32 -> bf16 converts (one launch: 4 weights + x) ----------------
__global__ __launch_bounds__(256) void cvt_all(
    const float* __restrict__ x,
    const float* __restrict__ w0, const float* __restrict__ w1,
    const float* __restrict__ w2, const float* __restrict__ w3,
    unsigned short* __restrict__ xb,
    unsigned short* __restrict__ o0, unsigned short* __restrict__ o1,
    unsigned short* __restrict__ o2, unsigned short* __restrict__ o3) {
    int y = blockIdx.y;
    const float* in;
    unsigned short* out;
    int idx;
    if (y < 4) {
        in  = (y == 0) ? w0 : (y == 1) ? w1 : (y == 2) ? w2 : w3;
        out = (y == 0) ? o0 : (y == 1) ? o1 : (y == 2) ? o2 : o3;
        idx = blockIdx.x * 256 + threadIdx.x;
    } else {
        in  = x;
        out = xb;
        idx = ((y - 4) * 1024 + blockIdx.x) * 256 + threadIdx.x;
    }
    float4 v = reinterpret_cast<const float4*>(in)[idx];
    ushort4 o;
    o.x = f2bf(v.x); o.y = f2bf(v.y); o.z = f2bf(v.z); o.w = f2bf(v.w);
    reinterpret_cast<ushort4*>(out)[idx] = o;
}

// ---------------- QKV projection: 128x128 tile, BK=64, 32x32 MFMA, dbuf+counted vmcnt ----------------
// 1D grid 768, XCD-chunked remap. Wave wv owns 64x64 (2x2 frags of 32x32).
__global__ __launch_bounds__(256, 2) void gemm_qkv(
    const unsigned short* __restrict__ xb,
    const unsigned short* __restrict__ Wqb, const unsigned short* __restrict__ Wkb,
    const unsigned short* __restrict__ Wvb,
    const float* __restrict__ bq, const float* __restrict__ bk, const float* __restrict__ bv,
    unsigned short* __restrict__ Qo, unsigned short* __restrict__ Ko, unsigned short* __restrict__ VTo) {
    __shared__ unsigned short Als[2][8192];   // [128 m][64 k] bf16, swizzled, 16KB/buf
    __shared__ unsigned short Bls[2][8192];   // [128 n][64 k]
    int L = blockIdx.x;
    int wg = (L & 7) * 96 + (L >> 3);         // bijective XCD-chunked remap (768 = 8*96)
    int z = wg >> 8, rem = wg & 255;
    int n0 = (rem & 7) * 128, m0 = (rem >> 3) * 128;
    const unsigned short* Bm = (z == 0) ? Wqb : (z == 1) ? Wkb : Wvb;
    const float* bias = (z == 0) ? bq : (z == 1) ? bk : bv;

    int t = threadIdx.x, wv = t >> 6, lane = t & 63;
    int q5 = lane & 31, hi = lane >> 5;
    int wm = wv >> 1, wn = wv & 1;
    const char* Ac = (const char*)xb;
    const char* Bc = (const char*)Bm;

    auto stage = [&](int bf, int k0) {
#pragma unroll
        for (int i = 0; i < 4; ++i) {
            int c = t + 256 * i;
            int kr = c >> 3, kc = ((c & 7) << 4) ^ ((kr & 7) << 4);
            gload_lds16b(Ac + ((size_t)(m0 + kr) * DMODEL + k0) * 2 + kc, (char*)&Als[bf][0] + c * 16);
        }
#pragma unroll
        for (int i = 0; i < 4; ++i) {
            int c = t + 256 * i;
            int kr = c >> 3, kc = ((c & 7) << 4) ^ ((kr & 7) << 4);
            gload_lds16b(Bc + ((size_t)(n0 + kr) * DMODEL + k0) * 2 + kc, (char*)&Bls[bf][0] + c * 16);
        }
    };

    f32x16 acc[2][2];
#pragma unroll
    for (int fm = 0; fm < 2; ++fm)
#pragma unroll
        for (int fn = 0; fn < 2; ++fn) acc[fm][fn] = (f32x16)0.f;

    stage(0, 0);
    int buf = 0;
    for (int k0 = 0; k0 < DMODEL; k0 += 64) {
        __builtin_amdgcn_s_barrier();
        if (k0 + 64 < DMODEL) {
            stage(buf ^ 1, k0 + 64);
            asm volatile("s_waitcnt vmcnt(8)" ::: "memory");
        } else {
            asm volatile("s_waitcnt vmcnt(0)" ::: "memory");
        }
        __builtin_amdgcn_sched_barrier(0);
        __builtin_amdgcn_s_barrier();
        __builtin_amdgcn_sched_barrier(0);

        const char* als = (const char*)&Als[buf][0];
        const char* bls = (const char*)&Bls[buf][0];
        __builtin_amdgcn_s_setprio(1);
#pragma unroll
        for (int ks = 0; ks < 4; ++ks) {
            int kb = ks * 32 + hi * 16;
            bf16x8 af[2], bfr[2];
#pragma unroll
            for (int fm = 0; fm < 2; ++fm) {
                int row = wm * 64 + fm * 32 + q5;
                af[fm] = *reinterpret_cast<const bf16x8*>(als + row * 128 + (kb ^ ((row & 7) << 4)));
            }
#pragma unroll
            for (int fn = 0; fn < 2; ++fn) {
                int row = wn * 64 + fn * 32 + q5;
                bfr[fn] = *reinterpret_cast<const bf16x8*>(bls + row * 128 + (kb ^ ((row & 7) << 4)));
            }
#pragma unroll
            for (int fm = 0; fm < 2; ++fm)
#pragma unroll
                for (int fn = 0; fn < 2; ++fn)
                    acc[fm][fn] = __builtin_amdgcn_mfma_f32_32x32x16_bf16(af[fm], bfr[fn], acc[fm][fn], 0, 0, 0);
        }
        __builtin_amdgcn_s_setprio(0);
        buf ^= 1;
    }

    // epilogue: D[m][n], col(n) = lane&31, row(m) = (r&3)+8*(r>>2)+4*hi
    float scale = (z == 0) ? (0.125f * LOG2E) : 1.0f;   // fold 1/sqrt(64)*log2(e) into Q
    int b = m0 >> 11;
#pragma unroll
    for (int fm = 0; fm < 2; ++fm) {
#pragma unroll
        for (int fn = 0; fn < 2; ++fn) {
            int col = n0 + wn * 64 + fn * 32 + q5;
            int h = col >> 6, dh = col & 63;
            float bi = bias[col];
            if (z == 2) {
#pragma unroll
                for (int rq = 0; rq < 4; ++rq) {
                    int s0 = ((m0 + wm * 64 + fm * 32 + 8 * rq + 4 * hi) & 2047);
                    ushort4 pk;
                    pk.x = f2bf(acc[fm][fn][4 * rq + 0] + bi);
                    pk.y = f2bf(acc[fm][fn][4 * rq + 1] + bi);
                    pk.z = f2bf(acc[fm][fn][4 * rq + 2] + bi);
                    pk.w = f2bf(acc[fm][fn][4 * rq + 3] + bi);
                    *reinterpret_cast<ushort4*>(&VTo[((size_t)((b * HD + h) * DHEAD + dh)) * SS + s0]) = pk;
                }
            } else {
                unsigned short* o = (z == 0) ? Qo : Ko;   // [bh][s][dh]
#pragma unroll
                for (int r = 0; r < 16; ++r) {
                    int s = (m0 + wm * 64 + fm * 32 + (r & 3) + 8 * (r >> 2) + 4 * hi) & 2047;
                    o[((size_t)((b * HD + h) * SS + s)) * DHEAD + dh] = f2bf((acc[fm][fn][r] + bi) * scale);
                }
            }
        }
    }
}

// ---------------- flash attention: 32x32 MFMA, in-reg softmax, XCD-swizzled (unchanged R9) ----------------
__global__ __launch_bounds__(256, 2) void attn_kernel(
    const unsigned short* __restrict__ Qb, const unsigned short* __restrict__ Kb,
    const unsigned short* __restrict__ VTb, unsigned short* __restrict__ ctxo) {
    __shared__ unsigned short Kls[2][8192];   // [128 t][64 dh] bf16, swizzled (16KB/buf)
    __shared__ unsigned short Vls[2][8192];   // [64 d][128 t]  bf16, swizzled
    int L = blockIdx.x + (int)gridDim.x * blockIdx.y;   // 0..511
    int wg = (L & 7) * 64 + (L >> 3);                   // bijective XCD-chunked remap
    int q0 = (wg & 15) * 128;
    int bh = wg >> 4;
    int t = threadIdx.x, wv = t >> 6, lane = t & 63;
    int q5 = lane & 31, hi = lane >> 5;
    const unsigned short* Qh  = Qb  + (size_t)bh * SS * DHEAD;
    const char* Khc  = (const char*)(Kb  + (size_t)bh * SS * DHEAD);
    const char* VThc = (const char*)(VTb + (size_t)bh * DHEAD * SS);
    int qr = q0 + wv * 32;

    bf16x8 qf[4];
#pragma unroll
    for (int m = 0; m < 4; ++m)
        qf[m] = ld8(&Qh[(size_t)(qr + q5) * DHEAD + m * 16 + hi * 8]);

    const __bf16 one_bf = (__bf16)1.0f;
    bf16x8 ones8 = {one_bf, one_bf, one_bf, one_bf, one_bf, one_bf, one_bf, one_bf};

    f32x16 oo[2];
    oo[0] = (f32x16)0.f; oo[1] = (f32x16)0.f;
    f32x16 ls = (f32x16)0.f;
    float mrun = 0.f;

    auto stage = [&](int buf, int t0) {
#pragma unroll
        for (int i = 0; i < 4; ++i) {
            int c = t + 256 * i;
            int kr = c >> 3, kc = ((c & 7) << 4) ^ ((kr & 7) << 4);
            gload_lds16b(Khc + (size_t)(t0 + kr) * 128 + kc, (char*)&Kls[buf][0] + c * 16);
        }
#pragma unroll
        for (int i = 0; i < 4; ++i) {
            int c = t + 256 * i;
            int vr = c >> 4, vc = ((c & 15) << 4) ^ ((vr & 7) << 4);
            gload_lds16b(VThc + ((size_t)vr * SS + t0) * 2 + vc, (char*)&Vls[buf][0] + c * 16);
        }
    };

    stage(0, 0);
    int buf = 0;

    for (int t0 = 0; t0 < SS; t0 += 128) {
        __builtin_amdgcn_s_barrier();
        if (t0 + 128 < SS) {
            stage(buf ^ 1, t0 + 128);
            asm volatile("s_waitcnt vmcnt(8)" ::: "memory");
        } else {
            asm volatile("s_waitcnt vmcnt(0)" ::: "memory");
        }
        __builtin_amdgcn_sched_barrier(0);
        __builtin_amdgcn_s_barrier();
        __builtin_amdgcn_sched_barrier(0);

        const char* kls = (const char*)&Kls[buf][0];
        const char* vls = (const char*)&Vls[buf][0];

#pragma unroll
        for (int half = 0; half < 2; ++half) {
            f32x16 sc[2];
            __builtin_amdgcn_s_setprio(1);
#pragma unroll
            for (int tb = 0; tb < 2; ++tb) {
                int row = (half * 2 + tb) * 32 + q5;
                int rsw = (row & 7) << 4;
                f32x16 s = (f32x16)0.f;
#pragma unroll
                for (int m = 0; m < 4; ++m) {
                    bf16x8 kf = *reinterpret_cast<const bf16x8*>(kls + row * 128 + ((m * 32 + hi * 16) ^ rsw));
                    s = __builtin_amdgcn_mfma_f32_32x32x16_bf16(kf, qf[m], s, 0, 0, 0);
                }
                sc[tb] = s;
            }
            __builtin_amdgcn_s_setprio(0);

            float mx[16];
#pragma unroll
            for (int r = 0; r < 16; ++r) mx[r] = fmaxf(sc[0][r], sc[1][r]);
#pragma unroll
            for (int st = 8; st; st >>= 1)
#pragma unroll
                for (int r = 0; r < st; ++r) mx[r] = fmaxf(mx[r], mx[r + st]);
            float lm = mx[0];

            if (__any(lm > mrun + 8.f)) {
                u32x2 sw = __builtin_amdgcn_permlane32_swap(__builtin_bit_cast(unsigned, lm),
                                                            __builtin_bit_cast(unsigned, lm), false, false);
                float rowmax = fmaxf(__builtin_bit_cast(float, sw[0]), __builtin_bit_cast(float, sw[1]));
                float mn = fmaxf(mrun, rowmax);
                float al = exp2f(mrun - mn);
                mrun = mn;
#pragma unroll
                for (int r = 0; r < 16; ++r) {
                    float alr = __shfl(al, (r & 3) + 8 * (r >> 2) + 4 * hi);
                    oo[0][r] *= alr; oo[1][r] *= alr; ls[r] *= alr;
                }
            }

#pragma unroll
            for (int tb = 0; tb < 2; ++tb)
#pragma unroll
                for (int r = 0; r < 16; ++r)
                    sc[tb][r] = exp2f(sc[tb][r] - mrun);

            u32x4 paw[4];
#pragma unroll
            for (int tb = 0; tb < 2; ++tb)
#pragma unroll
                for (int u2 = 0; u2 < 2; ++u2)
#pragma unroll
                    for (int e = 0; e < 2; ++e) {
                        unsigned wd = cvt_pk_bf16(sc[tb][8 * u2 + 2 * e], sc[tb][8 * u2 + 2 * e + 1]);
                        unsigned ws = cvt_pk_bf16(sc[tb][8 * u2 + 4 + 2 * e], sc[tb][8 * u2 + 4 + 2 * e + 1]);
                        u32x2 rr = __builtin_amdgcn_permlane32_swap(wd, ws, false, false);
                        paw[tb * 2 + u2][e] = rr[0];
                        paw[tb * 2 + u2][2 + e] = rr[1];
                    }

            __builtin_amdgcn_s_setprio(1);
#pragma unroll
            for (int dblk = 0; dblk < 2; ++dblk) {
                int row = dblk * 32 + q5;
                int rsw = (row & 7) << 4;
#pragma unroll
                for (int ks = 0; ks < 4; ++ks) {
                    bf16x8 vf = *reinterpret_cast<const bf16x8*>(
                        vls + row * 256 + ((half * 128 + ks * 32 + hi * 16) ^ rsw));
                    oo[dblk] = __builtin_amdgcn_mfma_f32_32x32x16_bf16(
                        __builtin_bit_cast(bf16x8, paw[ks]), vf, oo[dblk], 0, 0, 0);
                }
            }
#pragma unroll
            for (int ks = 0; ks < 4; ++ks)
                ls = __builtin_amdgcn_mfma_f32_32x32x16_bf16(
                    __builtin_bit_cast(bf16x8, paw[ks]), ones8, ls, 0, 0, 0);
            __builtin_amdgcn_s_setprio(0);
        }
        buf ^= 1;
    }

    int b = bh >> 4, h = bh & 15;
#pragma unroll
    for (int r = 0; r < 16; ++r) {
        float invr = 1.f / ls[r];
        int qrel = (r & 3) + 8 * (r >> 2) + 4 * hi;
        int s = qr + qrel;
        size_t base = ((size_t)(b * SS + s)) * DMODEL + h * DHEAD;
        ctxo[base + q5]      = f2bf(oo[0][r] * invr);
        ctxo[base + 32 + q5] = f2bf(oo[1][r] * invr);
    }
}

// ---------------- output projection: 128x64 tile, BK=64, 32x32 MFMA, dbuf+counted vmcnt ----------------
// 1D grid 512, XCD remap. Wave wv owns 64x32 (2x1 frags).
__global__ __launch_bounds__(256, 2) void gemm_proj(
    const unsigned short* __restrict__ ctxb, const unsigned short* __restrict__ Wdb,
    const float* __restrict__ bd, float* __restrict__ proj) {
    __shared__ unsigned short Als[2][8192];   // [128 m][64 k]
    __shared__ unsigned short Bls[2][4096];   // [64 n][64 k]
    int L = blockIdx.x;
    int wg = (L & 7) * 64 + (L >> 3);         // 512 = 8*64
    int n0 = (wg & 15) * 64, m0 = (wg >> 4) * 128;

    int t = threadIdx.x, wv = t >> 6, lane = t & 63;
    int q5 = lane & 31, hi = lane >> 5;
    int wm = wv >> 1, wn = wv & 1;
    const char* Ac = (const char*)ctxb;
    const char* Bc = (const char*)Wdb;

    auto stage = [&](int bf, int k0) {
#pragma unroll
        for (int i = 0; i < 4; ++i) {
            int c = t + 256 * i;
            int kr = c >> 3, kc = ((c & 7) << 4) ^ ((kr & 7) << 4);
            gload_lds16b(Ac + ((size_t)(m0 + kr) * DMODEL + k0) * 2 + kc, (char*)&Als[bf][0] + c * 16);
        }
#pragma unroll
        for (int i = 0; i < 2; ++i) {
            int c = t + 256 * i;
            int kr = c >> 3, kc = ((c & 7) << 4) ^ ((kr & 7) << 4);
            gload_lds16b(Bc + ((size_t)(n0 + kr) * DMODEL + k0) * 2 + kc, (char*)&Bls[bf][0] + c * 16);
        }
    };

    f32x16 acc[2];
    acc[0] = (f32x16)0.f; acc[1] = (f32x16)0.f;

    stage(0, 0);
    int buf = 0;
    for (int k0 = 0; k0 < DMODEL; k0 += 64) {
        __builtin_amdgcn_s_barrier();
        if (k0 + 64 < DMODEL) {
            stage(buf ^ 1, k0 + 64);
            asm volatile("s_waitcnt vmcnt(6)" ::: "memory");
        } else {
            asm volatile("s_waitcnt vmcnt(0)" ::: "memory");
        }
        __builtin_amdgcn_sched_barrier(0);
        __builtin_amdgcn_s_barrier();
        __builtin_amdgcn_sched_barrier(0);

        const char* als = (const char*)&Als[buf][0];
        const char* bls = (const char*)&Bls[buf][0];
        __builtin_amdgcn_s_setprio(1);
#pragma unroll
        for (int ks = 0; ks < 4; ++ks) {
            int kb = ks * 32 + hi * 16;
            bf16x8 af[2], bfr;
#pragma unroll
            for (int fm = 0; fm < 2; ++fm) {
                int row = wm * 64 + fm * 32 + q5;
                af[fm] = *reinterpret_cast<const bf16x8*>(als + row * 128 + (kb ^ ((row & 7) << 4)));
            }
            {
                int row = wn * 32 + q5;
                bfr = *reinterpret_cast<const bf16x8*>(bls + row * 128 + (kb ^ ((row & 7) << 4)));
            }
#pragma unroll
            for (int fm = 0; fm < 2; ++fm)
                acc[fm] = __builtin_amdgcn_mfma_f32_32x32x16_bf16(af[fm], bfr, acc[fm], 0, 0, 0);
        }
        __builtin_amdgcn_s_setprio(0);
        buf ^= 1;
    }

    int col = n0 + wn * 32 + q5;
    float bi = bd[col];
#pragma unroll
    for (int fm = 0; fm < 2; ++fm)
#pragma unroll
        for (int r = 0; r < 16; ++r) {
            int row = m0 + wm * 64 + fm * 32 + (r & 3) + 8 * (r >> 2) + 4 * hi;
            proj[(size_t)row * DMODEL + col] = acc[fm][r] + bi;
        }
}

// ---------------- LayerNorm over D=1024 ----------------
__global__ __launch_bounds__(256) void ln_kernel(const float* __restrict__ proj,
                                                 const float* __restrict__ g,
                                                 const float* __restrict__ bv,
                                                 float* __restrict__ out) {
    int row = blockIdx.x, t = threadIdx.x;
    float4 v = reinterpret_cast<const float4*>(proj + (size_t)row * DMODEL)[t];
    float s  = v.x + v.y + v.z + v.w;
    float s2 = v.x * v.x + v.y * v.y + v.z * v.z + v.w * v.w;
#pragma unroll
    for (int m = 1; m < 64; m <<= 1) { s += __shfl_xor(s, m); s2 += __shfl_xor(s2, m); }
    __shared__ float red[8];
    int wv = t >> 6, lane = t & 63;
    if (lane == 0) { red[wv] = s; red[wv + 4] = s2; }
    __syncthreads();
    s  = red[0] + red[1] + red[2] + red[3];
    s2 = red[4] + red[5] + red[6] + red[7];
    float mu  = s * (1.f / 1024.f);
    float var = s2 * (1.f / 1024.f) - mu * mu;
    float inv = rsqrtf(var + 1e-12f);
    float4 gv = reinterpret_cast<const float4*>(g)[t];
    float4 bb = reinterpret_cast<const float4*>(bv)[t];
    float4 ov;
    ov.x = (v.x - mu) * inv * gv.x + bb.x;
    ov.y = (v.y - mu) * inv * gv.y + bb.y;
    ov.z = (v.z - mu) * inv * gv.z + bb.z;
    ov.w = (v.w - mu) * inv * gv.w + bb.w;
    reinterpret_cast<float4*>(out + (size_t)row * DMODEL)[t] = ov;
}

extern "C" void kernel_launch(void* const* d_in, const int* in_sizes, int n_in,
                              void* d_out, int out_size, void* d_ws, size_t ws_size,
                              hipStream_t stream) {
    const float* x   = (const float*)d_in[0];
    const float* Wq  = (const float*)d_in[1];
    const float* bq  = (const float*)d_in[2];
    const float* Wk  = (const float*)d_in[3];
    const float* bk  = (const float*)d_in[4];
    const float* Wv  = (const float*)d_in[5];
    const float* bv  = (const float*)d_in[6];
    const float* Wd  = (const float*)d_in[7];
    const float* bd  = (const float*)d_in[8];
    const float* lng = (const float*)d_in[9];
    const float* lnb = (const float*)d_in[10];

    char* ws = (char*)d_ws;
    unsigned short* xb   = (unsigned short*)(ws);                    // 8 MB
    unsigned short* Wqb  = (unsigned short*)(ws + (8u  << 20));      // 2 MB each
    unsigned short* Wkb  = (unsigned short*)(ws + (10u << 20));
    unsigned short* Wvb  = (unsigned short*)(ws + (12u << 20));
    unsigned short* Wdb  = (unsigned short*)(ws + (14u << 20));
    unsigned short* Qb   = (unsigned short*)(ws + (16u << 20));      // 8 MB
    unsigned short* Kb   = (unsigned short*)(ws + (24u << 20));      // 8 MB
    unsigned short* VTb  = (unsigned short*)(ws + (32u << 20));      // 8 MB
    unsigned short* ctxb = (unsigned short*)(ws + (40u << 20));      // 8 MB
    float* proj = (float*)(ws + (16u << 20));  // 16 MB, aliases Q/K (dead after attention)

    cvt_all<<<dim3(1024, 8), 256, 0, stream>>>(x, Wq, Wk, Wv, Wd, xb, Wqb, Wkb, Wvb, Wdb);
    gemm_qkv<<<768, 256, 0, stream>>>(xb, Wqb, Wkb, Wvb, bq, bk, bv, Qb, Kb, VTb);
    attn_kernel<<<dim3(16, 32), 256, 0, stream>>>(Qb, Kb, VTb, ctxb);
    gemm_proj<<<512, 256, 0, stream>>>(ctxb, Wdb, bd, proj);
    ln_kernel<<<4096, 256, 0, stream>>>(proj, lng, lnb, (float*)d_out);
}